// Round 1
// baseline (213.230 us; speedup 1.0000x reference)
//
#include <hip/hip_runtime.h>
#include <hip/hip_bf16.h>
#include <math.h>

typedef float f32x4 __attribute__((ext_vector_type(4)));
typedef __bf16 bf16x8 __attribute__((ext_vector_type(8)));
typedef unsigned short u16;
typedef u16 u16x8 __attribute__((ext_vector_type(8)));
typedef u16 u16x4 __attribute__((ext_vector_type(4)));
typedef unsigned ui32x4 __attribute__((ext_vector_type(4)));

// round-to-nearest-even fp32 -> bf16
__device__ __forceinline__ u16 f2bf(float f) {
    unsigned u = __builtin_bit_cast(unsigned, f);
    u = (u + 0x7fffu + ((u >> 16) & 1u)) >> 16;
    return (u16)u;
}
// pack two fp32 -> two bf16 (round-half-up) in one v_perm: (hi16(b)<<16)|hi16(a)
__device__ __forceinline__ unsigned pack2_rhu(float a, float b) {
    return __builtin_amdgcn_perm(__builtin_bit_cast(unsigned, b) + 0x8000u,
                                 __builtin_bit_cast(unsigned, a) + 0x8000u,
                                 0x07060302u);
}

#if __has_builtin(__builtin_amdgcn_exp2f)
#define EXP2(x) __builtin_amdgcn_exp2f(x)
#else
#define EXP2(x) exp2f(x)
#endif

// async global->LDS 16B/lane: LDS dest = wave-uniform base + lane*16
__device__ __forceinline__ void gload16(const u16* g, u16* l) {
    __builtin_amdgcn_global_load_lds(
        (const __attribute__((address_space(1))) unsigned int*)(g),
        (__attribute__((address_space(3))) unsigned int*)(l), 16, 0, 0);
}

// Quad-exchange for P->A-fragment redistribution (replaces the P LDS round-trip).
// Inputs (per lane, A = dw[2h][s], B = dw[2h+1][s] across quads):
//   A = [A0,A1,A2,A3], B = [B0,B1,B2,B3]   (value held at quad q)
// Outputs: dlo = [A0,A2,B0,B2]  (A-frag dword j=s),  dhi = [A1,A3,B1,B3]  (dword j=2+s)
#if __has_builtin(__builtin_amdgcn_permlane32_swap) && __has_builtin(__builtin_amdgcn_permlane16_swap)
__device__ __forceinline__ void quad_swap(unsigned A, unsigned B, unsigned& dlo,
                                          unsigned& dhi, int quad) {
    auto t = __builtin_amdgcn_permlane32_swap(A, B, false, false);   // [A0,A1,B0,B1],[A2,A3,B2,B3]
    auto u = __builtin_amdgcn_permlane16_swap(t[0], t[1], false, false);
    dlo = u[0];  // [A0,A2,B0,B2]
    dhi = u[1];  // [A1,A3,B1,B3]
}
#else
__device__ __forceinline__ void quad_swap(unsigned A, unsigned B, unsigned& dlo,
                                          unsigned& dhi, int quad) {
    unsigned As = (unsigned)__shfl_xor((int)A, 32, 64);
    unsigned Bs = (unsigned)__shfl_xor((int)B, 32, 64);
    unsigned tx = (quad < 2) ? A : Bs;   // [A0,A1,B0,B1]
    unsigned ty = (quad < 2) ? As : B;   // [A2,A3,B2,B3]
    unsigned txs = (unsigned)__shfl_xor((int)tx, 16, 64);
    unsigned tys = (unsigned)__shfl_xor((int)ty, 16, 64);
    dlo = ((quad & 1) == 0) ? tx : tys;
    dhi = ((quad & 1) == 0) ? txs : ty;
}
#endif

// ---------------- fused cast fp32 -> bf16 for all 7 inputs ----------------
__global__ __launch_bounds__(256) void cast_all(
    const float* __restrict__ q, const float* __restrict__ k, const float* __restrict__ v,
    const float* __restrict__ wq, const float* __restrict__ wk, const float* __restrict__ wv,
    const float* __restrict__ wo, u16* __restrict__ dst) {
    int i = blockIdx.x * 256 + threadIdx.x;  // float4 index, grid covers 4194304 exactly
    const float* src;
    int off;
    if (i < 3145728) {
        int seg = i >> 20;
        src = (seg == 0) ? q : (seg == 1) ? k : v;
        off = i - (seg << 20);
    } else {
        int j = (i - 3145728) >> 18;
        src = (j == 0) ? wq : (j == 1) ? wk : (j == 2) ? wv : wo;
        off = (i - 3145728) - (j << 18);
    }
    float4 val = ((const float4*)src)[off];
    u16x4 o4;
    o4.x = f2bf(val.x); o4.y = f2bf(val.y); o4.z = f2bf(val.z); o4.w = f2bf(val.w);
    ((u16x4*)dst)[i] = o4;
}

// ---------------- fused QKV projection GEMM (async-LDS, XOR-swizzled) ----------------
// C = X @ W.T, M=4096, N=1024, K=1024. Tile 128x128, BK=64. 1-D grid of 768:
// blk = x*96 + z*32 + y  =>  blk%8 == y%8, so the 8 x-tiles of a (z,y) group land
// on one XCD (block->XCD ~ blk%8): shared X-rows (0.5 MB) + W (2 MB) stay L2-resident.
// NOTE: no min-waves hint — unified VGPR/AGPR file; capping waves spilled acc to
// scratch = 305 MB of HBM writes (round-4 bug).
__global__ __launch_bounds__(256) void qkv_gemm(
    const u16* __restrict__ Xq, const u16* __restrict__ Xk, const u16* __restrict__ Xv,
    const u16* __restrict__ Wq, const u16* __restrict__ Wk, const u16* __restrict__ Wv,
    u16* __restrict__ Qo, u16* __restrict__ Ko, u16* __restrict__ Vto) {
    constexpr int K = 1024;
    const int blk = blockIdx.x;
    const int xb = blk / 96;
    const int zb = (blk % 96) >> 5;
    const int yb = blk & 31;
    const int z = zb;
    const u16* __restrict__ A = (z == 0) ? Xq : (z == 1) ? Xk : Xv;
    const u16* __restrict__ W = (z == 0) ? Wq : (z == 1) ? Wk : Wv;
    u16* __restrict__ Out = (z == 0) ? Qo : (z == 1) ? Ko : Vto;

    __shared__ __align__(16) u16 As[128 * 64];  // 16 KB
    __shared__ __align__(16) u16 Bs[128 * 64];  // 16 KB

    const int t = threadIdx.x;
    const int lane = t & 63, wave = t >> 6;
    const int quad = lane >> 4, c = lane & 15, cx = c & 7;
    const int wr = (wave >> 1) * 64, wc = (wave & 1) * 64;
    const int rowA0 = yb * 128;
    const int colB0 = xb * 128;

    const int l3 = lane >> 3, l7 = lane & 7;
    const int chs = (l7 ^ l3) << 3;
    const u16* gA[4];
    const u16* gB[4];
    u16* lA[4];
    u16* lB[4];
#pragma unroll
    for (int i = 0; i < 4; ++i) {
        int row = wave * 32 + i * 8 + l3;
        gA[i] = A + (size_t)(rowA0 + row) * K + chs;
        gB[i] = W + (size_t)(colB0 + row) * K + chs;
        lA[i] = As + (wave * 256 + i * 64) * 8;
        lB[i] = Bs + (wave * 256 + i * 64) * 8;
    }

    const f32x4 zero4 = {0.f, 0.f, 0.f, 0.f};
    f32x4 acc[4][4];
#pragma unroll
    for (int i = 0; i < 4; ++i)
#pragma unroll
        for (int j = 0; j < 4; ++j) acc[i][j] = zero4;

    for (int kt = 0; kt < K; kt += 64) {
        __syncthreads();  // prior tile's reads complete
#pragma unroll
        for (int i = 0; i < 4; ++i) {
            gload16(gA[i] + kt, lA[i]);
            gload16(gB[i] + kt, lB[i]);
        }
        __syncthreads();  // staged data visible (vmcnt drained by barrier)
#pragma unroll
        for (int ks = 0; ks < 2; ++ks) {
            const int co = ((ks * 4 + quad) ^ cx) << 3;
            bf16x8 af[4], bfr[4];
#pragma unroll
            for (int i = 0; i < 4; ++i)
                af[i] = *(const bf16x8*)(As + (wr + i * 16 + c) * 64 + co);
#pragma unroll
            for (int j = 0; j < 4; ++j)
                bfr[j] = *(const bf16x8*)(Bs + (wc + j * 16 + c) * 64 + co);
            if (z == 2) {
#pragma unroll
                for (int i = 0; i < 4; ++i)
#pragma unroll
                    for (int j = 0; j < 4; ++j)
                        acc[i][j] = __builtin_amdgcn_mfma_f32_16x16x32_bf16(bfr[j], af[i], acc[i][j], 0, 0, 0);
            } else {
#pragma unroll
                for (int i = 0; i < 4; ++i)
#pragma unroll
                    for (int j = 0; j < 4; ++j)
                        acc[i][j] = __builtin_amdgcn_mfma_f32_16x16x32_bf16(af[i], bfr[j], acc[i][j], 0, 0, 0);
            }
        }
    }

    // 0.125 * log2(e): scores later exponentiate via exp2
    const float scale = (z == 0) ? 0.18033688011112042f : 1.0f;
#pragma unroll
    for (int i = 0; i < 4; ++i) {
#pragma unroll
        for (int j = 0; j < 4; ++j) {
#pragma unroll
            for (int r = 0; r < 4; ++r) {
                float v = acc[i][j][r];
                if (z == 2) {
                    int n = colB0 + wc + j * 16 + quad * 4 + r;  // feature (h*64+d)
                    int m = rowA0 + wr + i * 16 + c;             // token (b*2048+s)
                    int b = m >> 11, s = m & 2047, h = n >> 6, d = n & 63;
                    Out[((((b << 4) | h) << 6) + d) * 2048 + s] = f2bf(v);
                } else {
                    int m = rowA0 + wr + i * 16 + quad * 4 + r;  // token
                    int n = colB0 + wc + j * 16 + c;             // feature
                    int b = m >> 11, s = m & 2047, h = n >> 6, d = n & 63;
                    Out[((((b << 4) | h) * 2048 + s) << 6) + d] = f2bf(v * scale);
                }
            }
        }
    }
}

// ---------------- output projection GEMM (fp32 out, async-LDS, swizzled) ----------------
// Tile 64(M) x 128(N). 1-D grid 512: blk = yb + 64*xb => blk%8 == yb%8, so the 8
// x-tiles sharing A-rows cluster per XCD (A 1MB + W 2MB working set, L2-resident).
__global__ __launch_bounds__(256, 2) void out_gemm(const u16* __restrict__ A,
                                                   const u16* __restrict__ W,
                                                   float* __restrict__ Out) {
    constexpr int K = 1024;
    __shared__ __align__(16) u16 As[64 * 64];   // 8 KB
    __shared__ __align__(16) u16 Bs[128 * 64];  // 16 KB
    const int blk = blockIdx.x;
    const int yb = blk & 63;
    const int xb = blk >> 6;
    const int t = threadIdx.x;
    const int lane = t & 63, wave = t >> 6;
    const int quad = lane >> 4, c = lane & 15, cx = c & 7;
    const int wr = (wave >> 1) * 32, wc = (wave & 1) * 64;
    const int rowA0 = yb * 64;
    const int colB0 = xb * 128;

    const int l3 = lane >> 3, l7 = lane & 7;
    const int chs = (l7 ^ l3) << 3;
    const u16* gA[2];
    const u16* gB[4];
    u16* lA[2];
    u16* lB[4];
#pragma unroll
    for (int i = 0; i < 2; ++i) {
        int row = wave * 16 + i * 8 + l3;
        gA[i] = A + (size_t)(rowA0 + row) * K + chs;
        lA[i] = As + (wave * 128 + i * 64) * 8;
    }
#pragma unroll
    for (int i = 0; i < 4; ++i) {
        int row = wave * 32 + i * 8 + l3;
        gB[i] = W + (size_t)(colB0 + row) * K + chs;
        lB[i] = Bs + (wave * 256 + i * 64) * 8;
    }

    const f32x4 zero4 = {0.f, 0.f, 0.f, 0.f};
    f32x4 acc[2][4];
#pragma unroll
    for (int i = 0; i < 2; ++i)
#pragma unroll
        for (int j = 0; j < 4; ++j) acc[i][j] = zero4;

    for (int kt = 0; kt < K; kt += 64) {
        __syncthreads();
#pragma unroll
        for (int i = 0; i < 2; ++i) gload16(gA[i] + kt, lA[i]);
#pragma unroll
        for (int i = 0; i < 4; ++i) gload16(gB[i] + kt, lB[i]);
        __syncthreads();
#pragma unroll
        for (int ks = 0; ks < 2; ++ks) {
            const int co = ((ks * 4 + quad) ^ cx) << 3;
            bf16x8 af[2], bfr[4];
#pragma unroll
            for (int i = 0; i < 2; ++i)
                af[i] = *(const bf16x8*)(As + (wr + i * 16 + c) * 64 + co);
#pragma unroll
            for (int j = 0; j < 4; ++j)
                bfr[j] = *(const bf16x8*)(Bs + (wc + j * 16 + c) * 64 + co);
#pragma unroll
            for (int i = 0; i < 2; ++i)
#pragma unroll
                for (int j = 0; j < 4; ++j)
                    acc[i][j] = __builtin_amdgcn_mfma_f32_16x16x32_bf16(af[i], bfr[j], acc[i][j], 0, 0, 0);
        }
    }
#pragma unroll
    for (int i = 0; i < 2; ++i)
#pragma unroll
        for (int j = 0; j < 4; ++j)
#pragma unroll
            for (int r = 0; r < 4; ++r) {
                int m = rowA0 + wr + i * 16 + quad * 4 + r;
                int n = colB0 + wc + j * 16 + c;
                Out[(m << 10) + n] = acc[i][j][r];
            }
}

// ---------------- flash attention v7: in-register P via permlane quad-swaps ----------------
// v6 was LDS-bandwidth-bound (~60% bank-busy): 20 b128 + 8 b64 LDS ops/wave/iter, 2.1M
// bank-conflict cycles on the P round-trip, plus a serializing lgkmcnt(0) fence.
// v7 removes the P LDS round-trip entirely: the score->A-fragment redistribution is a pure
// quad-exchange at fixed lane-column (source: lane=q-col c, quad=4-key group; dest: lane=
// q-row c, quad=8-key chunk), done in-register with v_permlane32_swap + v_permlane16_swap
// (2 instrs per dword pair). LDS drops 48->32 KB, LDS ops/wave/iter 28 -> 16 (K/V only).
// Keeps 32 q-rows/wave (4 waves, 256 thr): splitting q finer would DUPLICATE the K/V
// fragment reads per wave and raise the LDS-bandwidth floor.
__global__ __launch_bounds__(256, 2) void flash_attn(const u16* __restrict__ Qp,
                                                     const u16* __restrict__ Kp,
                                                     const u16* __restrict__ Vt,
                                                     u16* __restrict__ Ob) {
    constexpr int S = 2048;
    const int blk = blockIdx.x;
    const int j = blk & 31;
    const int bh = ((j & 7) << 2) | (j >> 3);
    const int b = bh >> 4, h = bh & 15;
    const int t = threadIdx.x, wave = t >> 6, lane = t & 63;
    const int quad = lane >> 4, c = lane & 15, cx = c & 7;
    const int qw = (blk >> 5) * 128 + wave * 32;
    const u16* Qb = Qp + (bh * S + qw) * 64;
    const u16* Kb = Kp + (bh * S) * 64;
    const u16* Vb = Vt + bh * 64 * S;

    __shared__ __align__(16) u16 Ks[2][64 * 64];  // [key][dim], swizzled chunks
    __shared__ __align__(16) u16 Vs[2][64 * 64];  // [dim][key], swizzled chunks

    // Q fragments (B-operand): lane c holds Q[q=qt*16+c][dim=hf*32+quad*8+j]
    bf16x8 qf[2][2];
#pragma unroll
    for (int qt = 0; qt < 2; ++qt)
#pragma unroll
        for (int hf = 0; hf < 2; ++hf)
            qf[qt][hf] = *(const bf16x8*)(Qb + (qt * 16 + c) * 64 + hf * 32 + quad * 8);

    // all-ones bf16 B fragment for denominator MFMAs
    u16x8 ou;
#pragma unroll
    for (int i = 0; i < 8; ++i) ou[i] = 0x3F80;
    const bf16x8 onesf = __builtin_bit_cast(bf16x8, ou);

    // staging: wave w instr i covers physical chunks [w*128+i*64, +64)
    const int l3 = lane >> 3, l7 = lane & 7;
    const int chs = (l7 ^ l3) << 3;
    const u16* gK[2];
    const u16* gV[2];
    int lbase[2];
#pragma unroll
    for (int i = 0; i < 2; ++i) {
        int row = wave * 16 + i * 8 + l3;
        gK[i] = Kb + row * 64 + chs;    // += kv*64 per tile
        gV[i] = Vb + row * 2048 + chs;  // += kv per tile
        lbase[i] = (wave * 128 + i * 64) * 8;
    }
    // preload tile 0
#pragma unroll
    for (int i = 0; i < 2; ++i) {
        gload16(gK[i], &Ks[0][lbase[i]]);
        gload16(gV[i], &Vs[0][lbase[i]]);
    }
    __syncthreads();

    const f32x4 zero4 = {0.f, 0.f, 0.f, 0.f};
    f32x4 o[2][4];
    f32x4 ol[2];  // denominator: D[q][*] = row-sum of P (register-aligned with o)
#pragma unroll
    for (int qt = 0; qt < 2; ++qt) {
        ol[qt] = zero4;
#pragma unroll
        for (int t2 = 0; t2 < 4; ++t2) o[qt][t2] = zero4;
    }

    const int co0 = (quad ^ cx) << 3, co1 = ((4 + quad) ^ cx) << 3;

    for (int it = 0; it < S / 64; ++it) {
        const int cur = it & 1;
        // prefetch next tile into the other buffer (completes at this iter's barrier)
        if (it + 1 < S / 64) {
#pragma unroll
            for (int i = 0; i < 2; ++i) {
                gload16(gK[i] + (it + 1) * 4096, &Ks[cur ^ 1][lbase[i]]);
                gload16(gV[i] + (it + 1) * 64, &Vs[cur ^ 1][lbase[i]]);
            }
        }
        const u16* Kc = &Ks[cur][0];
        const u16* Vc = &Vs[cur][0];
        // ---- transposed scores: Sc^T[key][q] = K_tile * Q^T ----
        f32x4 sc[4][2];
#pragma unroll
        for (int kt = 0; kt < 4; ++kt) {
            const int krow = (kt * 16 + c) * 64;
            bf16x8 kf0 = *(const bf16x8*)(Kc + krow + co0);
            bf16x8 kf1 = *(const bf16x8*)(Kc + krow + co1);
#pragma unroll
            for (int qt = 0; qt < 2; ++qt) {
                f32x4 zz = zero4;
                zz = __builtin_amdgcn_mfma_f32_16x16x32_bf16(kf0, qf[qt][0], zz, 0, 0, 0);
                zz = __builtin_amdgcn_mfma_f32_16x16x32_bf16(kf1, qf[qt][1], zz, 0, 0, 0);
                sc[kt][qt] = zz;
            }
        }
        // ---- exp2 + pack + in-register quad-swap to A-fragment layout ----
        // lane (quad,c) holds keys kt*16+quad*4+r for q=qt*16+c; packed dword
        // n2 = 8*kt+2*quad+s. A-fragment af[h] dword j needs keys 32h+8*quad+2j:
        // dest quad pattern per dword = [A0,A2,B0,B2]/[A1,A3,B1,B3] with
        // A=dw[2h][s], B=dw[2h+1][s] -> permlane32_swap then permlane16_swap.
        bf16x8 af[2][2];
#pragma unroll
        for (int qt = 0; qt < 2; ++qt) {
            unsigned dw[4][2];
#pragma unroll
            for (int kt = 0; kt < 4; ++kt) {
                dw[kt][0] = pack2_rhu(EXP2(sc[kt][qt][0]), EXP2(sc[kt][qt][1]));
                dw[kt][1] = pack2_rhu(EXP2(sc[kt][qt][2]), EXP2(sc[kt][qt][3]));
            }
#pragma unroll
            for (int hh = 0; hh < 2; ++hh) {
                unsigned d0, d1, d2, d3;
                quad_swap(dw[2 * hh][0], dw[2 * hh + 1][0], d0, d2, quad);
                quad_swap(dw[2 * hh][1], dw[2 * hh + 1][1], d1, d3, quad);
                ui32x4 dd = {d0, d1, d2, d3};
                af[qt][hh] = __builtin_bit_cast(bf16x8, dd);
            }
        }
        // ---- O += P*V, l += P*ones (P entirely in registers) ----
#pragma unroll
        for (int qt = 0; qt < 2; ++qt) {
            ol[qt] = __builtin_amdgcn_mfma_f32_16x16x32_bf16(af[qt][0], onesf, ol[qt], 0, 0, 0);
            ol[qt] = __builtin_amdgcn_mfma_f32_16x16x32_bf16(af[qt][1], onesf, ol[qt], 0, 0, 0);
        }
#pragma unroll
        for (int t2 = 0; t2 < 4; ++t2) {
            const int vrow = (t2 * 16 + c) * 64;
            bf16x8 vf0 = *(const bf16x8*)(Vc + vrow + co0);
            bf16x8 vf1 = *(const bf16x8*)(Vc + vrow + co1);
#pragma unroll
            for (int qt = 0; qt < 2; ++qt) {
                o[qt][t2] = __builtin_amdgcn_mfma_f32_16x16x32_bf16(af[qt][0], vf0, o[qt][t2], 0, 0, 0);
                o[qt][t2] = __builtin_amdgcn_mfma_f32_16x16x32_bf16(af[qt][1], vf1, o[qt][t2], 0, 0, 0);
            }
        }
        __syncthreads();  // buffer lifecycle + drains prefetch vmcnt
    }
    // ---- epilogue: normalize and store [B,S,H,D]; ol[qt][r] is the row-sum for
    // row quad*4+r — exactly the row o[qt][..][r] holds. No shuffles needed. ----
#pragma unroll
    for (int qt = 0; qt < 2; ++qt)
#pragma unroll
        for (int r = 0; r < 4; ++r) {
            float inv = 1.f / ol[qt][r];
            int row = qw + qt * 16 + quad * 4 + r;
            int base = ((b * S + row) * 16 + h) * 64;
#pragma unroll
            for (int t2 = 0; t2 < 4; ++t2)
                Ob[base + t2 * 16 + c] = f2bf(o[qt][t2][r] * inv);
        }
}

extern "C" void kernel_launch(void* const* d_in, const int* in_sizes, int n_in,
                              void* d_out, int out_size, void* d_ws, size_t ws_size,
                              hipStream_t stream) {
    const float* q  = (const float*)d_in[0];
    const float* k  = (const float*)d_in[1];
    const float* v  = (const float*)d_in[2];
    const float* wq = (const float*)d_in[3];
    const float* wk = (const float*)d_in[4];
    const float* wv = (const float*)d_in[5];
    const float* wo = (const float*)d_in[6];

    u16* ws = (u16*)d_ws;
    u16* qb  = ws;              // 4194304 elems
    u16* kb  = ws + 4194304;
    u16* vb  = ws + 8388608;
    u16* wqb = ws + 12582912;   // 1048576 elems each
    u16* wkb = ws + 13631488;
    u16* wvb = ws + 14680064;
    u16* wob = ws + 15728640;
    u16* Qp  = ws + 16777216;   // [B,H,S,D]
    u16* Kp  = ws + 20971520;   // [B,H,S,D]
    u16* Vtp = ws + 25165824;   // [B,H,D,S]
    u16* Obf = ws + 29360128;   // [B,S,H,D]

    cast_all<<<16384, 256, 0, stream>>>(q, k, v, wq, wk, wv, wo, ws);

    // fused QKV projections: 1-D grid 768, XCD-grouped by (z, y)
    qkv_gemm<<<768, 256, 0, stream>>>(qb, kb, vb, wqb, wkb, wvb, Qp, Kp, Vtp);

    // flash attention: 1-D grid 512, XCD-grouped heads
    flash_attn<<<512, 256, 0, stream>>>(Qp, Kp, Vtp, Obf);

    // output projection: 1-D grid 512, XCD-grouped by y
    out_gemm<<<512, 256, 0, stream>>>(Obf, wob, (float*)d_out);
}

// Round 2
// 204.906 us; speedup vs baseline: 1.0406x; 1.0406x over previous
//
#include <hip/hip_runtime.h>
#include <hip/hip_bf16.h>
#include <math.h>

typedef float f32x4 __attribute__((ext_vector_type(4)));
typedef __bf16 bf16x8 __attribute__((ext_vector_type(8)));
typedef unsigned short u16;
typedef u16 u16x8 __attribute__((ext_vector_type(8)));
typedef u16 u16x4 __attribute__((ext_vector_type(4)));
typedef unsigned ui32x4 __attribute__((ext_vector_type(4)));

// round-to-nearest-even fp32 -> bf16
__device__ __forceinline__ u16 f2bf(float f) {
    unsigned u = __builtin_bit_cast(unsigned, f);
    u = (u + 0x7fffu + ((u >> 16) & 1u)) >> 16;
    return (u16)u;
}
// pack two fp32 -> two bf16 (round-half-up) in one v_perm: (hi16(b)<<16)|hi16(a)
__device__ __forceinline__ unsigned pack2_rhu(float a, float b) {
    return __builtin_amdgcn_perm(__builtin_bit_cast(unsigned, b) + 0x8000u,
                                 __builtin_bit_cast(unsigned, a) + 0x8000u,
                                 0x07060302u);
}

#if __has_builtin(__builtin_amdgcn_exp2f)
#define EXP2(x) __builtin_amdgcn_exp2f(x)
#else
#define EXP2(x) exp2f(x)
#endif

// async global->LDS 16B/lane: LDS dest = wave-uniform base + lane*16
__device__ __forceinline__ void gload16(const u16* g, u16* l) {
    __builtin_amdgcn_global_load_lds(
        (const __attribute__((address_space(1))) unsigned int*)(g),
        (__attribute__((address_space(3))) unsigned int*)(l), 16, 0, 0);
}

// Quad-exchange for P->A-fragment redistribution (in-register, no LDS).
#if __has_builtin(__builtin_amdgcn_permlane32_swap) && __has_builtin(__builtin_amdgcn_permlane16_swap)
__device__ __forceinline__ void quad_swap(unsigned A, unsigned B, unsigned& dlo,
                                          unsigned& dhi, int quad) {
    auto t = __builtin_amdgcn_permlane32_swap(A, B, false, false);   // [A0,A1,B0,B1],[A2,A3,B2,B3]
    auto u = __builtin_amdgcn_permlane16_swap(t[0], t[1], false, false);
    dlo = u[0];  // [A0,A2,B0,B2]
    dhi = u[1];  // [A1,A3,B1,B3]
}
#else
__device__ __forceinline__ void quad_swap(unsigned A, unsigned B, unsigned& dlo,
                                          unsigned& dhi, int quad) {
    unsigned As = (unsigned)__shfl_xor((int)A, 32, 64);
    unsigned Bs = (unsigned)__shfl_xor((int)B, 32, 64);
    unsigned tx = (quad < 2) ? A : Bs;   // [A0,A1,B0,B1]
    unsigned ty = (quad < 2) ? As : B;   // [A2,A3,B2,B3]
    unsigned txs = (unsigned)__shfl_xor((int)tx, 16, 64);
    unsigned tys = (unsigned)__shfl_xor((int)ty, 16, 64);
    dlo = ((quad & 1) == 0) ? tx : tys;
    dhi = ((quad & 1) == 0) ? txs : ty;
}
#endif

// ---------------- fused cast fp32 -> bf16 for all 7 inputs ----------------
__global__ __launch_bounds__(256) void cast_all(
    const float* __restrict__ q, const float* __restrict__ k, const float* __restrict__ v,
    const float* __restrict__ wq, const float* __restrict__ wk, const float* __restrict__ wv,
    const float* __restrict__ wo, u16* __restrict__ dst) {
    int i = blockIdx.x * 256 + threadIdx.x;  // float4 index, grid covers 4194304 exactly
    const float* src;
    int off;
    if (i < 3145728) {
        int seg = i >> 20;
        src = (seg == 0) ? q : (seg == 1) ? k : v;
        off = i - (seg << 20);
    } else {
        int j = (i - 3145728) >> 18;
        src = (j == 0) ? wq : (j == 1) ? wk : (j == 2) ? wv : wo;
        off = (i - 3145728) - (j << 18);
    }
    float4 val = ((const float4*)src)[off];
    u16x4 o4;
    o4.x = f2bf(val.x); o4.y = f2bf(val.y); o4.z = f2bf(val.z); o4.w = f2bf(val.w);
    ((u16x4*)dst)[i] = o4;
}

// ---------------- fused QKV projection GEMM (async-LDS, XOR-swizzled) ----------------
__global__ __launch_bounds__(256) void qkv_gemm(
    const u16* __restrict__ Xq, const u16* __restrict__ Xk, const u16* __restrict__ Xv,
    const u16* __restrict__ Wq, const u16* __restrict__ Wk, const u16* __restrict__ Wv,
    u16* __restrict__ Qo, u16* __restrict__ Ko, u16* __restrict__ Vto) {
    constexpr int K = 1024;
    const int blk = blockIdx.x;
    const int xb = blk / 96;
    const int zb = (blk % 96) >> 5;
    const int yb = blk & 31;
    const int z = zb;
    const u16* __restrict__ A = (z == 0) ? Xq : (z == 1) ? Xk : Xv;
    const u16* __restrict__ W = (z == 0) ? Wq : (z == 1) ? Wk : Wv;
    u16* __restrict__ Out = (z == 0) ? Qo : (z == 1) ? Ko : Vto;

    __shared__ __align__(16) u16 As[128 * 64];  // 16 KB
    __shared__ __align__(16) u16 Bs[128 * 64];  // 16 KB

    const int t = threadIdx.x;
    const int lane = t & 63, wave = t >> 6;
    const int quad = lane >> 4, c = lane & 15, cx = c & 7;
    const int wr = (wave >> 1) * 64, wc = (wave & 1) * 64;
    const int rowA0 = yb * 128;
    const int colB0 = xb * 128;

    const int l3 = lane >> 3, l7 = lane & 7;
    const int chs = (l7 ^ l3) << 3;
    const u16* gA[4];
    const u16* gB[4];
    u16* lA[4];
    u16* lB[4];
#pragma unroll
    for (int i = 0; i < 4; ++i) {
        int row = wave * 32 + i * 8 + l3;
        gA[i] = A + (size_t)(rowA0 + row) * K + chs;
        gB[i] = W + (size_t)(colB0 + row) * K + chs;
        lA[i] = As + (wave * 256 + i * 64) * 8;
        lB[i] = Bs + (wave * 256 + i * 64) * 8;
    }

    const f32x4 zero4 = {0.f, 0.f, 0.f, 0.f};
    f32x4 acc[4][4];
#pragma unroll
    for (int i = 0; i < 4; ++i)
#pragma unroll
        for (int j = 0; j < 4; ++j) acc[i][j] = zero4;

    for (int kt = 0; kt < K; kt += 64) {
        __syncthreads();  // prior tile's reads complete
#pragma unroll
        for (int i = 0; i < 4; ++i) {
            gload16(gA[i] + kt, lA[i]);
            gload16(gB[i] + kt, lB[i]);
        }
        __syncthreads();  // staged data visible (vmcnt drained by barrier)
#pragma unroll
        for (int ks = 0; ks < 2; ++ks) {
            const int co = ((ks * 4 + quad) ^ cx) << 3;
            bf16x8 af[4], bfr[4];
#pragma unroll
            for (int i = 0; i < 4; ++i)
                af[i] = *(const bf16x8*)(As + (wr + i * 16 + c) * 64 + co);
#pragma unroll
            for (int j = 0; j < 4; ++j)
                bfr[j] = *(const bf16x8*)(Bs + (wc + j * 16 + c) * 64 + co);
            if (z == 2) {
#pragma unroll
                for (int i = 0; i < 4; ++i)
#pragma unroll
                    for (int j = 0; j < 4; ++j)
                        acc[i][j] = __builtin_amdgcn_mfma_f32_16x16x32_bf16(bfr[j], af[i], acc[i][j], 0, 0, 0);
            } else {
#pragma unroll
                for (int i = 0; i < 4; ++i)
#pragma unroll
                    for (int j = 0; j < 4; ++j)
                        acc[i][j] = __builtin_amdgcn_mfma_f32_16x16x32_bf16(af[i], bfr[j], acc[i][j], 0, 0, 0);
            }
        }
    }

    // 0.125 * log2(e): scores later exponentiate via exp2
    const float scale = (z == 0) ? 0.18033688011112042f : 1.0f;
#pragma unroll
    for (int i = 0; i < 4; ++i) {
#pragma unroll
        for (int j = 0; j < 4; ++j) {
#pragma unroll
            for (int r = 0; r < 4; ++r) {
                float v = acc[i][j][r];
                if (z == 2) {
                    int n = colB0 + wc + j * 16 + quad * 4 + r;  // feature (h*64+d)
                    int m = rowA0 + wr + i * 16 + c;             // token (b*2048+s)
                    int b = m >> 11, s = m & 2047, h = n >> 6, d = n & 63;
                    Out[((((b << 4) | h) << 6) + d) * 2048 + s] = f2bf(v);
                } else {
                    int m = rowA0 + wr + i * 16 + quad * 4 + r;  // token
                    int n = colB0 + wc + j * 16 + c;             // feature
                    int b = m >> 11, s = m & 2047, h = n >> 6, d = n & 63;
                    Out[((((b << 4) | h) * 2048 + s) << 6) + d] = f2bf(v * scale);
                }
            }
        }
    }
}

// ---------------- output projection GEMM (fp32 out, async-LDS, swizzled) ----------------
__global__ __launch_bounds__(256, 2) void out_gemm(const u16* __restrict__ A,
                                                   const u16* __restrict__ W,
                                                   float* __restrict__ Out) {
    constexpr int K = 1024;
    __shared__ __align__(16) u16 As[64 * 64];   // 8 KB
    __shared__ __align__(16) u16 Bs[128 * 64];  // 16 KB
    const int blk = blockIdx.x;
    const int yb = blk & 63;
    const int xb = blk >> 6;
    const int t = threadIdx.x;
    const int lane = t & 63, wave = t >> 6;
    const int quad = lane >> 4, c = lane & 15, cx = c & 7;
    const int wr = (wave >> 1) * 32, wc = (wave & 1) * 64;
    const int rowA0 = yb * 64;
    const int colB0 = xb * 128;

    const int l3 = lane >> 3, l7 = lane & 7;
    const int chs = (l7 ^ l3) << 3;
    const u16* gA[2];
    const u16* gB[4];
    u16* lA[2];
    u16* lB[4];
#pragma unroll
    for (int i = 0; i < 2; ++i) {
        int row = wave * 16 + i * 8 + l3;
        gA[i] = A + (size_t)(rowA0 + row) * K + chs;
        lA[i] = As + (wave * 128 + i * 64) * 8;
    }
#pragma unroll
    for (int i = 0; i < 4; ++i) {
        int row = wave * 32 + i * 8 + l3;
        gB[i] = W + (size_t)(colB0 + row) * K + chs;
        lB[i] = Bs + (wave * 256 + i * 64) * 8;
    }

    const f32x4 zero4 = {0.f, 0.f, 0.f, 0.f};
    f32x4 acc[2][4];
#pragma unroll
    for (int i = 0; i < 2; ++i)
#pragma unroll
        for (int j = 0; j < 4; ++j) acc[i][j] = zero4;

    for (int kt = 0; kt < K; kt += 64) {
        __syncthreads();
#pragma unroll
        for (int i = 0; i < 2; ++i) gload16(gA[i] + kt, lA[i]);
#pragma unroll
        for (int i = 0; i < 4; ++i) gload16(gB[i] + kt, lB[i]);
        __syncthreads();
#pragma unroll
        for (int ks = 0; ks < 2; ++ks) {
            const int co = ((ks * 4 + quad) ^ cx) << 3;
            bf16x8 af[2], bfr[4];
#pragma unroll
            for (int i = 0; i < 2; ++i)
                af[i] = *(const bf16x8*)(As + (wr + i * 16 + c) * 64 + co);
#pragma unroll
            for (int j = 0; j < 4; ++j)
                bfr[j] = *(const bf16x8*)(Bs + (wc + j * 16 + c) * 64 + co);
#pragma unroll
            for (int i = 0; i < 2; ++i)
#pragma unroll
                for (int j = 0; j < 4; ++j)
                    acc[i][j] = __builtin_amdgcn_mfma_f32_16x16x32_bf16(af[i], bfr[j], acc[i][j], 0, 0, 0);
        }
    }
#pragma unroll
    for (int i = 0; i < 2; ++i)
#pragma unroll
        for (int j = 0; j < 4; ++j)
#pragma unroll
            for (int r = 0; r < 4; ++r) {
                int m = rowA0 + wr + i * 16 + quad * 4 + r;
                int n = colB0 + wc + j * 16 + c;
                Out[(m << 10) + n] = acc[i][j][r];
            }
}

// ---------------- flash attention v8: in-block split-K, 2x TLP ----------------
// v7 post-mortem: removing the P LDS round-trip (bank conflicts 2.1M->0) changed nothing
// -> not LDS-bound. MfmaUtil 28 / VALUBusy 41 / LDS ~40%, occupancy 17%: latency-bound
// with only 2 waves/SIMD (grid 512 x 4 waves = 8 waves/CU is the hard cap of the old
// decomposition; rows/wave must stay 32 or the per-wave K/V fragment reads double).
// v8: 512-thread blocks = 4 q-waves x 2 key-halves. kh=0 waves do keys 0..1023, kh=1
// waves keys 1024..2047, SAME 128 q-rows; each half has its own double-buffered K/V
// tiles (64 KB LDS). Halves combine (o=o0+o1, l=l0+l1 - exact for unscaled-exp softmax)
// through LDS at the end. 16 waves/CU (4/SIMD), per-wave iters 32->16, total LDS/HBM
// traffic unchanged.
__global__ __launch_bounds__(512, 4) void flash_attn(const u16* __restrict__ Qp,
                                                     const u16* __restrict__ Kp,
                                                     const u16* __restrict__ Vt,
                                                     u16* __restrict__ Ob) {
    constexpr int S = 2048;
    const int blk = blockIdx.x;
    const int j = blk & 31;
    const int bh = ((j & 7) << 2) | (j >> 3);
    const int b = bh >> 4, h = bh & 15;
    const int t = threadIdx.x, wave = t >> 6, lane = t & 63;
    const int wq = wave & 3, kh = wave >> 2;
    const int quad = lane >> 4, c = lane & 15, cx = c & 7;
    const int qw = (blk >> 5) * 128 + wq * 32;
    const u16* Qb = Qp + (bh * S + qw) * 64;
    const u16* Kb = Kp + (bh * S + kh * 1024) * 64;
    const u16* Vb = Vt + bh * 64 * S + kh * 1024;  // V^T [dim][key]

    // 64 KB: K tiles [kh][buf] at smem[0..16384), V tiles at smem[16384..32768)
    __shared__ __align__(16) u16 smem[32768];
    u16* const Kh = smem + kh * 8192;          // this half's two K buffers
    u16* const Vh = smem + 16384 + kh * 8192;  // this half's two V buffers

    // Q fragments (B-operand): lane c holds Q[q=qt*16+c][dim=hf*32+quad*8+j]
    bf16x8 qf[2][2];
#pragma unroll
    for (int qt = 0; qt < 2; ++qt)
#pragma unroll
        for (int hf = 0; hf < 2; ++hf)
            qf[qt][hf] = *(const bf16x8*)(Qb + (qt * 16 + c) * 64 + hf * 32 + quad * 8);

    // all-ones bf16 B fragment for denominator MFMAs
    u16x8 ou;
#pragma unroll
    for (int i = 0; i < 8; ++i) ou[i] = 0x3F80;
    const bf16x8 onesf = __builtin_bit_cast(bf16x8, ou);

    // staging: within a kh-group, wave wq instr i covers physical chunks [wq*128+i*64, +64)
    const int l3 = lane >> 3, l7 = lane & 7;
    const int chs = (l7 ^ l3) << 3;
    const u16* gK[2];
    const u16* gV[2];
    int lbase[2];
#pragma unroll
    for (int i = 0; i < 2; ++i) {
        int row = wq * 16 + i * 8 + l3;
        gK[i] = Kb + row * 64 + chs;    // += it*4096 per tile
        gV[i] = Vb + row * 2048 + chs;  // += it*64 per tile
        lbase[i] = (wq * 128 + i * 64) * 8;
    }
    // preload tile 0 of this half
#pragma unroll
    for (int i = 0; i < 2; ++i) {
        gload16(gK[i], Kh + lbase[i]);
        gload16(gV[i], Vh + lbase[i]);
    }
    __syncthreads();

    const f32x4 zero4 = {0.f, 0.f, 0.f, 0.f};
    f32x4 o[2][4];
    f32x4 ol[2];  // denominator: row-sum of P (register-aligned with o)
#pragma unroll
    for (int qt = 0; qt < 2; ++qt) {
        ol[qt] = zero4;
#pragma unroll
        for (int t2 = 0; t2 < 4; ++t2) o[qt][t2] = zero4;
    }

    const int co0 = (quad ^ cx) << 3, co1 = ((4 + quad) ^ cx) << 3;

    for (int it = 0; it < 16; ++it) {
        const int cur = it & 1;
        // prefetch next tile of this half into the other buffer
        if (it + 1 < 16) {
#pragma unroll
            for (int i = 0; i < 2; ++i) {
                gload16(gK[i] + (it + 1) * 4096, Kh + (cur ^ 1) * 4096 + lbase[i]);
                gload16(gV[i] + (it + 1) * 64, Vh + (cur ^ 1) * 4096 + lbase[i]);
            }
        }
        const u16* Kc = Kh + cur * 4096;
        const u16* Vc = Vh + cur * 4096;
        // ---- transposed scores: Sc^T[key][q] = K_tile * Q^T ----
        f32x4 sc[4][2];
#pragma unroll
        for (int kt = 0; kt < 4; ++kt) {
            const int krow = (kt * 16 + c) * 64;
            bf16x8 kf0 = *(const bf16x8*)(Kc + krow + co0);
            bf16x8 kf1 = *(const bf16x8*)(Kc + krow + co1);
#pragma unroll
            for (int qt = 0; qt < 2; ++qt) {
                f32x4 zz = zero4;
                zz = __builtin_amdgcn_mfma_f32_16x16x32_bf16(kf0, qf[qt][0], zz, 0, 0, 0);
                zz = __builtin_amdgcn_mfma_f32_16x16x32_bf16(kf1, qf[qt][1], zz, 0, 0, 0);
                sc[kt][qt] = zz;
            }
        }
        // ---- exp2 + pack + in-register quad-swap to A-fragment layout ----
        bf16x8 af[2][2];
#pragma unroll
        for (int qt = 0; qt < 2; ++qt) {
            unsigned dw[4][2];
#pragma unroll
            for (int kt = 0; kt < 4; ++kt) {
                dw[kt][0] = pack2_rhu(EXP2(sc[kt][qt][0]), EXP2(sc[kt][qt][1]));
                dw[kt][1] = pack2_rhu(EXP2(sc[kt][qt][2]), EXP2(sc[kt][qt][3]));
            }
#pragma unroll
            for (int hh = 0; hh < 2; ++hh) {
                unsigned d0, d1, d2, d3;
                quad_swap(dw[2 * hh][0], dw[2 * hh + 1][0], d0, d2, quad);
                quad_swap(dw[2 * hh][1], dw[2 * hh + 1][1], d1, d3, quad);
                ui32x4 dd = {d0, d1, d2, d3};
                af[qt][hh] = __builtin_bit_cast(bf16x8, dd);
            }
        }
        // ---- O += P*V, l += P*ones (P entirely in registers) ----
#pragma unroll
        for (int qt = 0; qt < 2; ++qt) {
            ol[qt] = __builtin_amdgcn_mfma_f32_16x16x32_bf16(af[qt][0], onesf, ol[qt], 0, 0, 0);
            ol[qt] = __builtin_amdgcn_mfma_f32_16x16x32_bf16(af[qt][1], onesf, ol[qt], 0, 0, 0);
        }
#pragma unroll
        for (int t2 = 0; t2 < 4; ++t2) {
            const int vrow = (t2 * 16 + c) * 64;
            bf16x8 vf0 = *(const bf16x8*)(Vc + vrow + co0);
            bf16x8 vf1 = *(const bf16x8*)(Vc + vrow + co1);
#pragma unroll
            for (int qt = 0; qt < 2; ++qt) {
                o[qt][t2] = __builtin_amdgcn_mfma_f32_16x16x32_bf16(af[qt][0], vf0, o[qt][t2], 0, 0, 0);
                o[qt][t2] = __builtin_amdgcn_mfma_f32_16x16x32_bf16(af[qt][1], vf1, o[qt][t2], 0, 0, 0);
            }
        }
        __syncthreads();  // buffer lifecycle + drains prefetch vmcnt
    }
    // ---- combine halves through LDS (tiles dead after final barrier above) ----
    // per (wq,lane): 41-dword padded slot (41 mod 32 = 9, coprime -> conflict-free)
    float* const cb = ((float*)smem) + ((wq << 6) | lane) * 41;
    if (kh == 1) {
        int idx = 0;
#pragma unroll
        for (int qt = 0; qt < 2; ++qt)
#pragma unroll
            for (int t2 = 0; t2 < 4; ++t2)
#pragma unroll
                for (int r = 0; r < 4; ++r) cb[idx++] = o[qt][t2][r];
#pragma unroll
        for (int qt = 0; qt < 2; ++qt)
#pragma unroll
            for (int r = 0; r < 4; ++r) cb[idx++] = ol[qt][r];
    }
    __syncthreads();
    if (kh == 0) {
        int idx = 0;
#pragma unroll
        for (int qt = 0; qt < 2; ++qt)
#pragma unroll
            for (int t2 = 0; t2 < 4; ++t2)
#pragma unroll
                for (int r = 0; r < 4; ++r) o[qt][t2][r] += cb[idx++];
#pragma unroll
        for (int qt = 0; qt < 2; ++qt)
#pragma unroll
            for (int r = 0; r < 4; ++r) ol[qt][r] += cb[idx++];
        // ---- epilogue: normalize and store [B,S,H,D]; ol[qt][r] is the row-sum for
        // row quad*4+r — exactly the row o[qt][..][r] holds. ----
#pragma unroll
        for (int qt = 0; qt < 2; ++qt)
#pragma unroll
            for (int r = 0; r < 4; ++r) {
                float inv = 1.f / ol[qt][r];
                int row = qw + qt * 16 + quad * 4 + r;
                int base = ((b * S + row) * 16 + h) * 64;
#pragma unroll
                for (int t2 = 0; t2 < 4; ++t2)
                    Ob[base + t2 * 16 + c] = f2bf(o[qt][t2][r] * inv);
            }
    }
}

extern "C" void kernel_launch(void* const* d_in, const int* in_sizes, int n_in,
                              void* d_out, int out_size, void* d_ws, size_t ws_size,
                              hipStream_t stream) {
    const float* q  = (const float*)d_in[0];
    const float* k  = (const float*)d_in[1];
    const float* v  = (const float*)d_in[2];
    const float* wq = (const float*)d_in[3];
    const float* wk = (const float*)d_in[4];
    const float* wv = (const float*)d_in[5];
    const float* wo = (const float*)d_in[6];

    u16* ws = (u16*)d_ws;
    u16* qb  = ws;              // 4194304 elems
    u16* kb  = ws + 4194304;
    u16* vb  = ws + 8388608;
    u16* wqb = ws + 12582912;   // 1048576 elems each
    u16* wkb = ws + 13631488;
    u16* wvb = ws + 14680064;
    u16* wob = ws + 15728640;
    u16* Qp  = ws + 16777216;   // [B,H,S,D]
    u16* Kp  = ws + 20971520;   // [B,H,S,D]
    u16* Vtp = ws + 25165824;   // [B,H,D,S]
    u16* Obf = ws + 29360128;   // [B,S,H,D]

    cast_all<<<16384, 256, 0, stream>>>(q, k, v, wq, wk, wv, wo, ws);

    // fused QKV projections: 1-D grid 768, XCD-grouped by (z, y)
    qkv_gemm<<<768, 256, 0, stream>>>(qb, kb, vb, wqb, wkb, wvb, Qp, Kp, Vtp);

    // flash attention: 1-D grid 512 x 512 threads, in-block split-K
    flash_attn<<<512, 512, 0, stream>>>(Qp, Kp, Vtp, Obf);

    // output projection: 1-D grid 512, XCD-grouped by y
    out_gemm<<<512, 256, 0, stream>>>(Obf, wob, (float*)d_out);
}